// Round 1
// baseline (788.994 us; speedup 1.0000x reference)
//
#include <hip/hip_runtime.h>
#include <hip/hip_bf16.h>

// ---- problem constants ----
#define B_    1024
#define D_    384
#define Q_    65536
#define N_    66560            // B_ + Q_
#define TOPK_ 128

// ---- select kernel histogram config ----
#define NB_   4096
#define LO_   (-8.0f)
#define HI_   (8.0f)
#define CAP_  1024

typedef __bf16 bf16x8 __attribute__((ext_vector_type(8)));
typedef float  f32x4  __attribute__((ext_vector_type(4)));

// RNE float -> bf16 (bit-level, avoids __bf16 conversion support questions)
__device__ __forceinline__ unsigned short f2bf(float x) {
  unsigned int u = __float_as_uint(x);
  unsigned int r = (u + 0x7fffu + ((u >> 16) & 1u)) >> 16;
  return (unsigned short)r;
}

__device__ __forceinline__ void gld_lds16(const void* g, void* l) {
  __builtin_amdgcn_global_load_lds(
      (__attribute__((address_space(1))) void*)(g),
      (__attribute__((address_space(3))) void*)(l), 16, 0, 0);
}

// ---------------------------------------------------------------------------
// Normalize rgb/ir feats. Writes bf16 z (unscaled, Ball role) and bf16 z/temp
// (A role). temp computed on-device from epoch.
// grid: 2*B_ blocks x 64 threads (1 wave). block < B_ -> rgb, else ir.
// ---------------------------------------------------------------------------
__global__ __launch_bounds__(64) void k_normalize(
    const float* __restrict__ rgb, const float* __restrict__ ir,
    const int* __restrict__ ep,
    unsigned short* __restrict__ zrA, unsigned short* __restrict__ ziA,
    unsigned short* __restrict__ zrU, unsigned short* __restrict__ ziU)
{
  int r = blockIdx.x & (B_ - 1);
  bool isIr = blockIdx.x >= B_;
  const float* src = (isIr ? ir : rgb) + (size_t)r * D_;
  unsigned short* dA = (isIr ? ziA : zrA) + (size_t)r * D_;
  unsigned short* dU = (isIr ? ziU : zrU) + (size_t)r * D_;
  int t = threadIdx.x;
  float x[6]; float ss = 0.f;
  #pragma unroll
  for (int k = 0; k < 6; ++k) { x[k] = src[t + 64*k]; ss += x[k]*x[k]; }
  #pragma unroll
  for (int off = 32; off > 0; off >>= 1) ss += __shfl_down(ss, off);
  ss = __shfl(ss, 0);
  float inv = 1.0f / fmaxf(sqrtf(ss), 1e-12f);

  int e = ep[0];
  float temp;
  if (e >= 10) temp = 0.05f;
  else {
    float p = (float)e * 0.1f;
    temp = 0.05f + 0.075f * (1.0f + cosf(3.14159265358979323846f * p));
  }
  float itemp = 1.0f / temp;

  #pragma unroll
  for (int k = 0; k < 6; ++k) {
    float z = x[k] * inv;
    dU[t + 64*k] = f2bf(z);
    dA[t + 64*k] = f2bf(z * itemp);
  }
}

// ---------------------------------------------------------------------------
// Build Ball bf16 [N_][D_] = [z_other (bf16 copy) ; queue (f32->bf16)]
// 4 elements / thread.
// ---------------------------------------------------------------------------
__global__ __launch_bounds__(256) void k_build_ball(
    const unsigned short* __restrict__ zU, const float* __restrict__ queue,
    unsigned short* __restrict__ ball)
{
  size_t u = (size_t)blockIdx.x * 256 + threadIdx.x;
  size_t i = u * 4;
  const size_t zElems = (size_t)B_ * D_;
  if (i < zElems) {
    *(uint2*)(ball + i) = *(const uint2*)(zU + i);
  } else {
    float4 v = *(const float4*)(queue + (i - zElems));
    ushort4 o;
    o.x = f2bf(v.x); o.y = f2bf(v.y); o.z = f2bf(v.z); o.w = f2bf(v.w);
    *(ushort4*)(ball + i) = o;
  }
}

// ---------------------------------------------------------------------------
// bf16 MFMA GEMM: C[slab_row][col] = A_scaled[r0+slab_row] . Ball[col]
// 128x128 tile, BK=64, 256 threads (2x2 waves, each 64x64 = 4x4 frags 16x16x32).
// global_load_lds 16B staging, linear LDS. Epilogue: diag extract + poison.
// grid: (N_/128, SR/128)
// ---------------------------------------------------------------------------
#define BK_ 64
__global__ __launch_bounds__(256) void k_gemm(
    const unsigned short* __restrict__ A,     // [B_][D_] scaled bf16
    const unsigned short* __restrict__ ball,  // [N_][D_] bf16
    float* __restrict__ C,                    // [SR][N_]
    float* __restrict__ diag,                 // [B_] (this dir)
    int r0)
{
  __shared__ unsigned short As[128 * BK_];
  __shared__ unsigned short Bs[128 * BK_];
  const int tid  = threadIdx.x;
  const int wave = tid >> 6, lane = tid & 63;
  const int wm = wave >> 1, wn = wave & 1;
  const int mbase = blockIdx.y * 128;   // local slab row base
  const int nbase = blockIdx.x * 128;
  const unsigned short* Ab = A    + (size_t)(r0 + mbase) * D_;
  const unsigned short* Bb = ball + (size_t)nbase * D_;

  f32x4 acc[4][4];
  #pragma unroll
  for (int m = 0; m < 4; ++m)
    #pragma unroll
    for (int n = 0; n < 4; ++n)
      #pragma unroll
      for (int r = 0; r < 4; ++r) acc[m][n][r] = 0.0f;

  for (int ks = 0; ks < D_; ks += BK_) {
    #pragma unroll
    for (int i = 0; i < 4; ++i) {
      int f = i * 256 + tid;            // 16B chunk id, 1024 chunks per tile
      int rr = f >> 3, c = f & 7;
      const unsigned short* ga = Ab + (size_t)rr * D_ + ks + c * 8;
      const unsigned short* gb = Bb + (size_t)rr * D_ + ks + c * 8;
      unsigned short* la = As + (size_t)(i * 256 + wave * 64) * 8; // wave-uniform base
      unsigned short* lb = Bs + (size_t)(i * 256 + wave * 64) * 8;
      gld_lds16(ga, la);
      gld_lds16(gb, lb);
    }
    __syncthreads();

    const int lr = lane & 15, lk = (lane >> 4) * 8;
    #pragma unroll
    for (int kk = 0; kk < BK_; kk += 32) {
      bf16x8 af[4], bq[4];
      #pragma unroll
      for (int m = 0; m < 4; ++m)
        af[m] = *(const bf16x8*)(As + (wm*64 + m*16 + lr) * BK_ + kk + lk);
      #pragma unroll
      for (int n = 0; n < 4; ++n)
        bq[n] = *(const bf16x8*)(Bs + (wn*64 + n*16 + lr) * BK_ + kk + lk);
      #pragma unroll
      for (int m = 0; m < 4; ++m)
        #pragma unroll
        for (int n = 0; n < 4; ++n)
          acc[m][n] = __builtin_amdgcn_mfma_f32_16x16x32_bf16(af[m], bq[n], acc[m][n], 0, 0, 0);
    }
    __syncthreads();
  }

  // Epilogue. D layout: col = lane&15, row = (lane>>4)*4 + reg.
  const int lr = lane & 15;
  const int rowq = (lane >> 4) * 4;
  #pragma unroll
  for (int m = 0; m < 4; ++m) {
    #pragma unroll
    for (int n = 0; n < 4; ++n) {
      int col = nbase + wn*64 + n*16 + lr;
      #pragma unroll
      for (int r = 0; r < 4; ++r) {
        int srow = mbase + wm*64 + m*16 + rowq + r;
        float x = acc[m][n][r];
        int grow = r0 + srow;
        if (col == grow) { diag[grow] = x; x = -1e30f; }
        C[(size_t)srow * N_ + col] = x;
      }
    }
  }
}

// ---------------------------------------------------------------------------
// Per-row exact top-128 + exp-sum + loss. One block (256 thr) per slab row.
// Sweep 1: sum exp + 4096-bin histogram. Find boundary bin (cum-from-top >=128).
// Sweep 2: collect all values with bin >= boundary (>=128 guaranteed), exact
// rank among candidates, Delta = sum over rank<128 of (e^{2v} - e^{v}).
// ---------------------------------------------------------------------------
__global__ __launch_bounds__(256) void k_select(
    const float* __restrict__ C, const float* __restrict__ diag,
    float* __restrict__ rowloss, int r0)
{
  __shared__ int   hist[NB_];
  __shared__ float vals[CAP_];
  __shared__ int   idxs[CAP_];
  __shared__ float red[256];
  __shared__ int   sh_b, sh_cnt;

  const int t = threadIdx.x;
  const int grow = r0 + blockIdx.x;
  const float* p = C + (size_t)blockIdx.x * N_;

  for (int i = t; i < NB_; i += 256) hist[i] = 0;
  if (t == 0) sh_cnt = 0;
  __syncthreads();

  const float invw = (float)NB_ / (HI_ - LO_);
  float sum = 0.f;
  for (int it = 0; it < N_ / 1024; ++it) {
    float4 v = *(const float4*)(p + (size_t)(it * 256 + t) * 4);
    float vv[4] = {v.x, v.y, v.z, v.w};
    #pragma unroll
    for (int e = 0; e < 4; ++e) {
      float x = vv[e];
      sum += __expf(x);
      float bf = fminf(fmaxf((x - LO_) * invw, 0.0f), (float)(NB_ - 1));
      atomicAdd(&hist[(int)bf], 1);
    }
  }
  red[t] = sum;
  __syncthreads();
  for (int s = 128; s > 0; s >>= 1) { if (t < s) red[t] += red[t + s]; __syncthreads(); }
  float sumExp = red[0];
  __syncthreads();

  if (t == 0) {
    int cum = 0; int b = 0;
    for (int i = NB_ - 1; i >= 0; --i) { cum += hist[i]; if (cum >= TOPK_) { b = i; break; } }
    sh_b = b;
  }
  __syncthreads();
  const int bb = sh_b;

  for (int it = 0; it < N_ / 1024; ++it) {
    int j0 = (it * 256 + t) * 4;
    float4 v = *(const float4*)(p + j0);
    float vv[4] = {v.x, v.y, v.z, v.w};
    #pragma unroll
    for (int e = 0; e < 4; ++e) {
      float x = vv[e];
      float bf = fminf(fmaxf((x - LO_) * invw, 0.0f), (float)(NB_ - 1));
      if ((int)bf >= bb) {
        int s = atomicAdd(&sh_cnt, 1);
        if (s < CAP_) { vals[s] = x; idxs[s] = j0 + e; }
      }
    }
  }
  __syncthreads();
  int Ccnt = sh_cnt < CAP_ ? sh_cnt : CAP_;

  float dsum = 0.f;
  for (int i = t; i < Ccnt; i += 256) {
    float v = vals[i]; int id = idxs[i];
    int rank = 0;
    for (int k = 0; k < Ccnt; ++k) {
      float u = vals[k];
      rank += (u > v) || (u == v && idxs[k] < id);
    }
    if (rank < TOPK_) dsum += __expf(2.f * v) - __expf(v);
  }
  red[t] = dsum;
  __syncthreads();
  for (int s = 128; s > 0; s >>= 1) { if (t < s) red[t] += red[t + s]; __syncthreads(); }

  if (t == 0) {
    float d = diag[grow];
    float total = sumExp + __expf(d) + red[0];
    rowloss[grow] = logf(total) - d;
  }
}

__global__ __launch_bounds__(256) void k_final(
    const float* __restrict__ rowloss, float* __restrict__ out)
{
  __shared__ float red[256];
  int t = threadIdx.x;
  float s = 0.f;
  for (int i = t; i < 2 * B_; i += 256) s += rowloss[i];
  red[t] = s;
  __syncthreads();
  for (int k = 128; k > 0; k >>= 1) { if (t < k) red[t] += red[t + k]; __syncthreads(); }
  if (t == 0) out[0] = red[0] * (1.0f / (2.0f * B_));
}

// ---------------------------------------------------------------------------
extern "C" void kernel_launch(void* const* d_in, const int* in_sizes, int n_in,
                              void* d_out, int out_size, void* d_ws, size_t ws_size,
                              hipStream_t stream)
{
  const float* rgb_feat = (const float*)d_in[0];
  const float* ir_feat  = (const float*)d_in[1];
  const float* rgb_q    = (const float*)d_in[2];
  const float* ir_q     = (const float*)d_in[3];
  const int*   epoch    = (const int*)d_in[4];

  char* ws = (char*)d_ws;
  size_t off = 0;
  auto alloc = [&](size_t bytes) -> char* {
    char* p = ws + off;
    off = (off + bytes + 255) & ~(size_t)255;
    return p;
  };

  unsigned short* zrA = (unsigned short*)alloc((size_t)B_ * D_ * 2); // rgb_z / temp
  unsigned short* ziA = (unsigned short*)alloc((size_t)B_ * D_ * 2); // ir_z  / temp
  unsigned short* zrU = (unsigned short*)alloc((size_t)B_ * D_ * 2); // rgb_z
  unsigned short* ziU = (unsigned short*)alloc((size_t)B_ * D_ * 2); // ir_z
  float* diag    = (float*)alloc((size_t)2 * B_ * 4);
  float* rowloss = (float*)alloc((size_t)2 * B_ * 4);
  unsigned short* ball = (unsigned short*)alloc((size_t)N_ * D_ * 2);

  size_t avail = ws_size > off ? ws_size - off : 0;
  int SR = (int)(avail / ((size_t)N_ * 4));
  SR &= ~127;
  if (SR > B_) SR = B_;
  if (SR < 128) SR = 128;   // assumes ws_size >= ~92 MB
  float* slab = (float*)(ws + off);

  k_normalize<<<dim3(2 * B_), dim3(64), 0, stream>>>(
      rgb_feat, ir_feat, epoch, zrA, ziA, zrU, ziU);

  for (int dir = 0; dir < 2; ++dir) {
    const unsigned short* Amat   = (dir == 0) ? zrA : ziA;
    const unsigned short* zOther = (dir == 0) ? ziU : zrU;
    const float*          queue  = (dir == 0) ? ir_q : rgb_q;
    float* diagD = diag    + dir * B_;
    float* lossD = rowloss + dir * B_;

    k_build_ball<<<dim3(((size_t)N_ * D_ / 4 + 255) / 256), dim3(256), 0, stream>>>(
        zOther, queue, ball);

    for (int r0 = 0; r0 < B_; r0 += SR) {
      int cur = (B_ - r0) < SR ? (B_ - r0) : SR;
      k_gemm<<<dim3(N_ / 128, cur / 128), dim3(256), 0, stream>>>(
          Amat, ball, slab, diagD, r0);
      k_select<<<dim3(cur), dim3(256), 0, stream>>>(slab, diagD, lossD, r0);
    }
  }

  k_final<<<dim3(1), dim3(256), 0, stream>>>(rowloss, (float*)d_out);
}

// Round 2
// 567.687 us; speedup vs baseline: 1.3898x; 1.3898x over previous
//
#include <hip/hip_runtime.h>
#include <hip/hip_bf16.h>

// ---- problem constants ----
#define B_    1024
#define D_    384
#define Q_    65536
#define N_    66560            // B_ + Q_
#define TOPK_ 128

typedef __bf16 bf16x8 __attribute__((ext_vector_type(8)));
typedef float  f32x4  __attribute__((ext_vector_type(4)));
typedef unsigned short u16;
typedef u16 u16x8 __attribute__((ext_vector_type(8)));

// RNE float -> bf16 (bit-level)
__device__ __forceinline__ unsigned short f2bf(float x) {
  unsigned int u = __float_as_uint(x);
  unsigned int r = (u + 0x7fffu + ((u >> 16) & 1u)) >> 16;
  return (unsigned short)r;
}

__device__ __forceinline__ void gld_lds16(const void* g, void* l) {
  __builtin_amdgcn_global_load_lds(
      (__attribute__((address_space(1))) void*)(g),
      (__attribute__((address_space(3))) void*)(l), 16, 0, 0);
}

// monotone key <-> bf16 bits
__device__ __forceinline__ unsigned int bf2key(unsigned int u) {
  return u ^ ((u & 0x8000u) ? 0xFFFFu : 0x8000u);
}
__device__ __forceinline__ float key2val(unsigned int k) {
  unsigned int u = (k & 0x8000u) ? (k ^ 0x8000u) : (~k & 0xFFFFu);
  return __uint_as_float(u << 16);
}

// ---------------------------------------------------------------------------
// Normalize rgb/ir feats -> bf16 z (Ball role) and bf16 z/temp (A role).
// ---------------------------------------------------------------------------
__global__ __launch_bounds__(64) void k_normalize(
    const float* __restrict__ rgb, const float* __restrict__ ir,
    const int* __restrict__ ep,
    u16* __restrict__ zrA, u16* __restrict__ ziA,
    u16* __restrict__ zrU, u16* __restrict__ ziU)
{
  int r = blockIdx.x & (B_ - 1);
  bool isIr = blockIdx.x >= B_;
  const float* src = (isIr ? ir : rgb) + (size_t)r * D_;
  u16* dA = (isIr ? ziA : zrA) + (size_t)r * D_;
  u16* dU = (isIr ? ziU : zrU) + (size_t)r * D_;
  int t = threadIdx.x;
  float x[6]; float ss = 0.f;
  #pragma unroll
  for (int k = 0; k < 6; ++k) { x[k] = src[t + 64*k]; ss += x[k]*x[k]; }
  #pragma unroll
  for (int off = 32; off > 0; off >>= 1) ss += __shfl_down(ss, off);
  ss = __shfl(ss, 0);
  float inv = 1.0f / fmaxf(sqrtf(ss), 1e-12f);

  int e = ep[0];
  float temp;
  if (e >= 10) temp = 0.05f;
  else {
    float p = (float)e * 0.1f;
    temp = 0.05f + 0.075f * (1.0f + cosf(3.14159265358979323846f * p));
  }
  float itemp = 1.0f / temp;

  #pragma unroll
  for (int k = 0; k < 6; ++k) {
    float z = x[k] * inv;
    dU[t + 64*k] = f2bf(z);
    dA[t + 64*k] = f2bf(z * itemp);
  }
}

// ---------------------------------------------------------------------------
// Build Ball bf16 [N_][D_] = [z_other (bf16 copy) ; queue (f32->bf16)]
// 8 elements / thread.
// ---------------------------------------------------------------------------
__global__ __launch_bounds__(256) void k_build_ball(
    const u16* __restrict__ zU, const float* __restrict__ queue,
    u16* __restrict__ ball)
{
  size_t i = ((size_t)blockIdx.x * 256 + threadIdx.x) * 8;
  const size_t zElems = (size_t)B_ * D_;
  if (i < zElems) {
    *(uint4*)(ball + i) = *(const uint4*)(zU + i);
  } else {
    const float* q = queue + (i - zElems);
    float4 a = *(const float4*)q;
    float4 b = *(const float4*)(q + 4);
    u16x8 o;
    o[0] = f2bf(a.x); o[1] = f2bf(a.y); o[2] = f2bf(a.z); o[3] = f2bf(a.w);
    o[4] = f2bf(b.x); o[5] = f2bf(b.y); o[6] = f2bf(b.z); o[7] = f2bf(b.w);
    *(u16x8*)(ball + i) = o;
  }
}

// ---------------------------------------------------------------------------
// bf16 MFMA GEMM -> bf16 logits slab. 128x128 tile, BK=64, 4 waves (2x2).
// Epilogue: extract diag (f32) then poison with -60.
// ---------------------------------------------------------------------------
#define BK_ 64
__global__ __launch_bounds__(256) void k_gemm(
    const u16* __restrict__ A,     // [B_][D_] scaled bf16
    const u16* __restrict__ ball,  // [N_][D_] bf16
    u16* __restrict__ C,           // [SR][N_] bf16 logits
    float* __restrict__ diag,      // [B_]
    int r0)
{
  __shared__ u16 As[128 * BK_];
  __shared__ u16 Bs[128 * BK_];
  const int tid  = threadIdx.x;
  const int wave = tid >> 6, lane = tid & 63;
  const int wm = wave >> 1, wn = wave & 1;
  const int mbase = blockIdx.y * 128;
  const int nbase = blockIdx.x * 128;
  const u16* Ab = A    + (size_t)(r0 + mbase) * D_;
  const u16* Bb = ball + (size_t)nbase * D_;

  f32x4 acc[4][4];
  #pragma unroll
  for (int m = 0; m < 4; ++m)
    #pragma unroll
    for (int n = 0; n < 4; ++n)
      #pragma unroll
      for (int r = 0; r < 4; ++r) acc[m][n][r] = 0.0f;

  for (int ks = 0; ks < D_; ks += BK_) {
    #pragma unroll
    for (int i = 0; i < 4; ++i) {
      int f = i * 256 + tid;
      int rr = f >> 3, c = f & 7;
      const u16* ga = Ab + (size_t)rr * D_ + ks + c * 8;
      const u16* gb = Bb + (size_t)rr * D_ + ks + c * 8;
      u16* la = As + (size_t)(i * 256 + wave * 64) * 8;
      u16* lb = Bs + (size_t)(i * 256 + wave * 64) * 8;
      gld_lds16(ga, la);
      gld_lds16(gb, lb);
    }
    __syncthreads();

    const int lr = lane & 15, lk = (lane >> 4) * 8;
    #pragma unroll
    for (int kk = 0; kk < BK_; kk += 32) {
      bf16x8 af[4], bq[4];
      #pragma unroll
      for (int m = 0; m < 4; ++m)
        af[m] = *(const bf16x8*)(As + (wm*64 + m*16 + lr) * BK_ + kk + lk);
      #pragma unroll
      for (int n = 0; n < 4; ++n)
        bq[n] = *(const bf16x8*)(Bs + (wn*64 + n*16 + lr) * BK_ + kk + lk);
      #pragma unroll
      for (int m = 0; m < 4; ++m)
        #pragma unroll
        for (int n = 0; n < 4; ++n)
          acc[m][n] = __builtin_amdgcn_mfma_f32_16x16x32_bf16(af[m], bq[n], acc[m][n], 0, 0, 0);
    }
    __syncthreads();
  }

  // D layout: col = lane&15, row = (lane>>4)*4 + reg.
  const int lr = lane & 15;
  const int rowq = (lane >> 4) * 4;
  #pragma unroll
  for (int m = 0; m < 4; ++m) {
    #pragma unroll
    for (int n = 0; n < 4; ++n) {
      int col = nbase + wn*64 + n*16 + lr;
      #pragma unroll
      for (int r = 0; r < 4; ++r) {
        int srow = mbase + wm*64 + m*16 + rowq + r;
        float x = acc[m][n][r];
        int grow = r0 + srow;
        if (col == grow) { diag[grow] = x; x = -60.0f; }
        C[(size_t)srow * N_ + col] = f2bf(x);
      }
    }
  }
}

// ---------------------------------------------------------------------------
// Per-row exact top-128 + exp-sum + loss via full 64K-key bf16 histogram.
// One block (256 thr) per row. Single streaming sweep (unroll-8 ushort8).
// 32768 packed uint words (2x16-bit counts) = 128 KB LDS.
// ---------------------------------------------------------------------------
__global__ __launch_bounds__(256) void k_select(
    const u16* __restrict__ C, const float* __restrict__ diag,
    float* __restrict__ rowloss, int r0)
{
  __shared__ __align__(16) unsigned int h[32768];   // 128 KB
  __shared__ float fred[256];
  __shared__ unsigned int csum[256];
  __shared__ float ddelta;

  const int t = threadIdx.x;
  const int grow = r0 + blockIdx.x;
  const u16x8* p = (const u16x8*)(C + (size_t)blockIdx.x * N_);

  uint4* h4 = (uint4*)h;
  #pragma unroll
  for (int i = 0; i < 32; ++i) h4[i * 256 + t] = make_uint4(0,0,0,0);
  if (t == 0) ddelta = 0.f;
  __syncthreads();

  // ---- streaming sweep: expsum + full-key histogram ----
  float esum = 0.f;
  #pragma unroll 1
  for (int base = 0; base < 8192; base += 2048) {   // 8192 of 8320 ushort8 chunks
    u16x8 v[8];
    #pragma unroll
    for (int j = 0; j < 8; ++j) v[j] = p[base + j * 256 + t];
    #pragma unroll
    for (int j = 0; j < 8; ++j) {
      #pragma unroll
      for (int e = 0; e < 8; ++e) {
        unsigned int u = (unsigned int)(unsigned short)v[j][e];
        unsigned int k = bf2key(u);
        atomicAdd(&h[k >> 1], 1u << ((k & 1u) << 4));
        esum += __expf(__uint_as_float(u << 16));
      }
    }
  }
  if (t < 128) {                                     // tail: chunks 8192..8319
    u16x8 v = p[8192 + t];
    #pragma unroll
    for (int e = 0; e < 8; ++e) {
      unsigned int u = (unsigned int)(unsigned short)v[e];
      unsigned int k = bf2key(u);
      atomicAdd(&h[k >> 1], 1u << ((k & 1u) << 4));
      esum += __expf(__uint_as_float(u << 16));
    }
  }
  fred[t] = esum;
  __syncthreads();
  #pragma unroll
  for (int s = 128; s > 0; s >>= 1) { if (t < s) fred[t] += fred[t + s]; __syncthreads(); }

  // ---- chunk sums (thread t owns keys [t*256, t*256+256) = words [t*128, +128)) ----
  unsigned int S = 0;
  #pragma unroll 1
  for (int i = 0; i < 128; ++i) {
    unsigned int w = h[t * 128 + ((i + t) & 127)];   // rotated to avoid bank conflict
    S += (w & 0xFFFFu) + (w >> 16);
  }
  csum[t] = S;
  __syncthreads();

  // ---- suffix-inclusive scan (Hillis-Steele) ----
  unsigned int a = S;
  #pragma unroll
  for (int s = 1; s < 256; s <<= 1) {
    unsigned int add = (t + s < 256) ? csum[t + s] : 0u;
    __syncthreads();
    a += add; csum[t] = a;
    __syncthreads();
  }
  int above = (t < 255) ? (int)csum[t + 1] : 0;      // elements strictly above my chunk
  int need = TOPK_ - above;

  // ---- boundary chunk(s): walk keys from top, take counts, accumulate Delta ----
  if (need > 0 && S > 0) {
    float ds = 0.f;
    for (int i = 127; i >= 0 && need > 0; --i) {
      unsigned int w = h[t * 128 + i];
      int chi = (int)(w >> 16);
      if (chi > 0) {
        int c = chi < need ? chi : need;
        float v = key2val((unsigned int)(t * 256 + 2 * i + 1));
        ds += (float)c * (__expf(2.f * v) - __expf(v));
        need -= c;
      }
      if (need > 0) {
        int clo = (int)(w & 0xFFFFu);
        if (clo > 0) {
          int c = clo < need ? clo : need;
          float v = key2val((unsigned int)(t * 256 + 2 * i));
          ds += (float)c * (__expf(2.f * v) - __expf(v));
          need -= c;
        }
      }
    }
    atomicAdd(&ddelta, ds);
  }
  __syncthreads();

  if (t == 0) {
    float d = diag[grow];
    rowloss[grow] = logf(fred[0] + __expf(d) + ddelta) - d;
  }
}

__global__ __launch_bounds__(256) void k_final(
    const float* __restrict__ rowloss, float* __restrict__ out)
{
  __shared__ float red[256];
  int t = threadIdx.x;
  float s = 0.f;
  for (int i = t; i < 2 * B_; i += 256) s += rowloss[i];
  red[t] = s;
  __syncthreads();
  for (int k = 128; k > 0; k >>= 1) { if (t < k) red[t] += red[t + k]; __syncthreads(); }
  if (t == 0) out[0] = red[0] * (1.0f / (2.0f * B_));
}

// ---------------------------------------------------------------------------
extern "C" void kernel_launch(void* const* d_in, const int* in_sizes, int n_in,
                              void* d_out, int out_size, void* d_ws, size_t ws_size,
                              hipStream_t stream)
{
  const float* rgb_feat = (const float*)d_in[0];
  const float* ir_feat  = (const float*)d_in[1];
  const float* rgb_q    = (const float*)d_in[2];
  const float* ir_q     = (const float*)d_in[3];
  const int*   epoch    = (const int*)d_in[4];

  char* ws = (char*)d_ws;
  size_t off = 0;
  auto alloc = [&](size_t bytes) -> char* {
    char* p = ws + off;
    off = (off + bytes + 255) & ~(size_t)255;
    return p;
  };

  u16* zrA = (u16*)alloc((size_t)B_ * D_ * 2);
  u16* ziA = (u16*)alloc((size_t)B_ * D_ * 2);
  u16* zrU = (u16*)alloc((size_t)B_ * D_ * 2);
  u16* ziU = (u16*)alloc((size_t)B_ * D_ * 2);
  float* diag    = (float*)alloc((size_t)2 * B_ * 4);
  float* rowloss = (float*)alloc((size_t)2 * B_ * 4);
  u16* ball = (u16*)alloc((size_t)N_ * D_ * 2);

  size_t avail = ws_size > off ? ws_size - off : 0;
  int SR = (int)(avail / ((size_t)N_ * 2));
  SR &= ~127;
  if (SR > B_) SR = B_;
  if (SR < 128) SR = 128;
  u16* slab = (u16*)(ws + off);

  k_normalize<<<dim3(2 * B_), dim3(64), 0, stream>>>(
      rgb_feat, ir_feat, epoch, zrA, ziA, zrU, ziU);

  for (int dir = 0; dir < 2; ++dir) {
    const u16*   Amat   = (dir == 0) ? zrA : ziA;
    const u16*   zOther = (dir == 0) ? ziU : zrU;
    const float* queue  = (dir == 0) ? ir_q : rgb_q;
    float* diagD = diag    + dir * B_;
    float* lossD = rowloss + dir * B_;

    k_build_ball<<<dim3((unsigned)((size_t)N_ * D_ / 8 / 256)), dim3(256), 0, stream>>>(
        zOther, queue, ball);

    for (int r0 = 0; r0 < B_; r0 += SR) {
      int cur = (B_ - r0) < SR ? (B_ - r0) : SR;
      k_gemm<<<dim3(N_ / 128, cur / 128), dim3(256), 0, stream>>>(
          Amat, ball, slab, diagD, r0);
      k_select<<<dim3(cur), dim3(256), 0, stream>>>(slab, diagD, lossD, r0);
    }
  }

  k_final<<<dim3(1), dim3(256), 0, stream>>>(rowloss, (float*)d_out);
}

// Round 3
// 406.159 us; speedup vs baseline: 1.9426x; 1.3977x over previous
//
#include <hip/hip_runtime.h>
#include <hip/hip_bf16.h>

// ---- problem constants ----
#define B_    1024
#define D_    384
#define Q_    65536
#define N_    66560            // B_ + Q_
#define TOPK_ 128

#define NBIN_ 4096             // histogram bins = key >> 4
#define CAP_  2048             // boundary-bin candidate cap

typedef __bf16 bf16x8 __attribute__((ext_vector_type(8)));
typedef float  f32x4  __attribute__((ext_vector_type(4)));
typedef unsigned short u16;
typedef u16 u16x8 __attribute__((ext_vector_type(8)));

// RNE float -> bf16 (bit-level)
__device__ __forceinline__ unsigned short f2bf(float x) {
  unsigned int u = __float_as_uint(x);
  unsigned int r = (u + 0x7fffu + ((u >> 16) & 1u)) >> 16;
  return (unsigned short)r;
}

__device__ __forceinline__ void gld_lds16(const void* g, void* l) {
  __builtin_amdgcn_global_load_lds(
      (__attribute__((address_space(1))) void*)(g),
      (__attribute__((address_space(3))) void*)(l), 16, 0, 0);
}

// monotone key from bf16 bits
__device__ __forceinline__ unsigned int bf2key(unsigned int u) {
  return u ^ ((u & 0x8000u) ? 0xFFFFu : 0x8000u);
}

// ---------------------------------------------------------------------------
// Normalize rgb/ir feats -> bf16 z (Ball role) and bf16 z/temp (A role).
// ---------------------------------------------------------------------------
__global__ __launch_bounds__(64) void k_normalize(
    const float* __restrict__ rgb, const float* __restrict__ ir,
    const int* __restrict__ ep,
    u16* __restrict__ zrA, u16* __restrict__ ziA,
    u16* __restrict__ zrU, u16* __restrict__ ziU)
{
  int r = blockIdx.x & (B_ - 1);
  bool isIr = blockIdx.x >= B_;
  const float* src = (isIr ? ir : rgb) + (size_t)r * D_;
  u16* dA = (isIr ? ziA : zrA) + (size_t)r * D_;
  u16* dU = (isIr ? ziU : zrU) + (size_t)r * D_;
  int t = threadIdx.x;
  float x[6]; float ss = 0.f;
  #pragma unroll
  for (int k = 0; k < 6; ++k) { x[k] = src[t + 64*k]; ss += x[k]*x[k]; }
  #pragma unroll
  for (int off = 32; off > 0; off >>= 1) ss += __shfl_down(ss, off);
  ss = __shfl(ss, 0);
  float inv = 1.0f / fmaxf(sqrtf(ss), 1e-12f);

  int e = ep[0];
  float temp;
  if (e >= 10) temp = 0.05f;
  else {
    float p = (float)e * 0.1f;
    temp = 0.05f + 0.075f * (1.0f + cosf(3.14159265358979323846f * p));
  }
  float itemp = 1.0f / temp;

  #pragma unroll
  for (int k = 0; k < 6; ++k) {
    float z = x[k] * inv;
    dU[t + 64*k] = f2bf(z);
    dA[t + 64*k] = f2bf(z * itemp);
  }
}

// ---------------------------------------------------------------------------
// Build Ball bf16 [N_][D_] = [z_other (bf16 copy) ; queue (f32->bf16)]
// ---------------------------------------------------------------------------
__global__ __launch_bounds__(256) void k_build_ball(
    const u16* __restrict__ zU, const float* __restrict__ queue,
    u16* __restrict__ ball)
{
  size_t i = ((size_t)blockIdx.x * 256 + threadIdx.x) * 8;
  const size_t zElems = (size_t)B_ * D_;
  if (i < zElems) {
    *(uint4*)(ball + i) = *(const uint4*)(zU + i);
  } else {
    const float* q = queue + (i - zElems);
    float4 a = *(const float4*)q;
    float4 b = *(const float4*)(q + 4);
    u16x8 o;
    o[0] = f2bf(a.x); o[1] = f2bf(a.y); o[2] = f2bf(a.z); o[3] = f2bf(a.w);
    o[4] = f2bf(b.x); o[5] = f2bf(b.y); o[6] = f2bf(b.z); o[7] = f2bf(b.w);
    *(u16x8*)(ball + i) = o;
  }
}

// ---------------------------------------------------------------------------
// bf16 MFMA GEMM -> bf16 logits slab. 128x128 tile, BK=64, 4 waves (2x2).
// Epilogue: extract diag (f32) then poison with -60.
// ---------------------------------------------------------------------------
#define BK_ 64
__global__ __launch_bounds__(256) void k_gemm(
    const u16* __restrict__ A,     // [B_][D_] scaled bf16
    const u16* __restrict__ ball,  // [N_][D_] bf16
    u16* __restrict__ C,           // [SR][N_] bf16 logits
    float* __restrict__ diag,      // [B_]
    int r0)
{
  __shared__ u16 As[128 * BK_];
  __shared__ u16 Bs[128 * BK_];
  const int tid  = threadIdx.x;
  const int wave = tid >> 6, lane = tid & 63;
  const int wm = wave >> 1, wn = wave & 1;
  const int mbase = blockIdx.y * 128;
  const int nbase = blockIdx.x * 128;
  const u16* Ab = A    + (size_t)(r0 + mbase) * D_;
  const u16* Bb = ball + (size_t)nbase * D_;

  f32x4 acc[4][4];
  #pragma unroll
  for (int m = 0; m < 4; ++m)
    #pragma unroll
    for (int n = 0; n < 4; ++n)
      #pragma unroll
      for (int r = 0; r < 4; ++r) acc[m][n][r] = 0.0f;

  for (int ks = 0; ks < D_; ks += BK_) {
    #pragma unroll
    for (int i = 0; i < 4; ++i) {
      int f = i * 256 + tid;
      int rr = f >> 3, c = f & 7;
      const u16* ga = Ab + (size_t)rr * D_ + ks + c * 8;
      const u16* gb = Bb + (size_t)rr * D_ + ks + c * 8;
      u16* la = As + (size_t)(i * 256 + wave * 64) * 8;
      u16* lb = Bs + (size_t)(i * 256 + wave * 64) * 8;
      gld_lds16(ga, la);
      gld_lds16(gb, lb);
    }
    __syncthreads();

    const int lr = lane & 15, lk = (lane >> 4) * 8;
    #pragma unroll
    for (int kk = 0; kk < BK_; kk += 32) {
      bf16x8 af[4], bq[4];
      #pragma unroll
      for (int m = 0; m < 4; ++m)
        af[m] = *(const bf16x8*)(As + (wm*64 + m*16 + lr) * BK_ + kk + lk);
      #pragma unroll
      for (int n = 0; n < 4; ++n)
        bq[n] = *(const bf16x8*)(Bs + (wn*64 + n*16 + lr) * BK_ + kk + lk);
      #pragma unroll
      for (int m = 0; m < 4; ++m)
        #pragma unroll
        for (int n = 0; n < 4; ++n)
          acc[m][n] = __builtin_amdgcn_mfma_f32_16x16x32_bf16(af[m], bq[n], acc[m][n], 0, 0, 0);
    }
    __syncthreads();
  }

  // D layout: col = lane&15, row = (lane>>4)*4 + reg.
  const int lr = lane & 15;
  const int rowq = (lane >> 4) * 4;
  #pragma unroll
  for (int m = 0; m < 4; ++m) {
    #pragma unroll
    for (int n = 0; n < 4; ++n) {
      int col = nbase + wn*64 + n*16 + lr;
      #pragma unroll
      for (int r = 0; r < 4; ++r) {
        int srow = mbase + wm*64 + m*16 + rowq + r;
        float x = acc[m][n][r];
        int grow = r0 + srow;
        if (col == grow) { diag[grow] = x; x = -60.0f; }
        C[(size_t)srow * N_ + col] = f2bf(x);
      }
    }
  }
}

// ---------------------------------------------------------------------------
// Per-row exact top-128 + exp-sum + loss. 2-sweep radix select:
//   sweep 1: expsum + 4096-bin histogram (key>>4), 16 KB LDS
//   scan   : exact boundary bin b*, exact count A above it
//   sweep 2: bins > b* -> accumulate e^{2v}-e^{v}; == b* -> collect + rank
// ~26 KB LDS -> 4 blocks/CU co-resident (vs 1 before).
// ---------------------------------------------------------------------------
__global__ __launch_bounds__(256) void k_select(
    const u16* __restrict__ C, const float* __restrict__ diag,
    float* __restrict__ rowloss, int r0)
{
  __shared__ unsigned int hist[NBIN_];   // 16 KB
  __shared__ float vals[CAP_];           // 8 KB
  __shared__ float fred[256];
  __shared__ unsigned int csum[256];
  __shared__ int sh_bstar, sh_above, sh_cnt;

  const int t = threadIdx.x;
  const int grow = r0 + blockIdx.x;
  const u16x8* p = (const u16x8*)(C + (size_t)blockIdx.x * N_);

  uint4* h4 = (uint4*)hist;
  #pragma unroll
  for (int i = 0; i < 4; ++i) h4[i * 256 + t] = make_uint4(0,0,0,0);
  if (t == 0) sh_cnt = 0;
  __syncthreads();

  // ---- sweep 1: expsum + histogram ----
  float es0 = 0.f, es1 = 0.f;
  #pragma unroll 1
  for (int base = 0; base < 8192; base += 2048) {
    u16x8 v[8];
    #pragma unroll
    for (int j = 0; j < 8; ++j) v[j] = p[base + j * 256 + t];
    #pragma unroll
    for (int j = 0; j < 8; ++j) {
      #pragma unroll
      for (int e = 0; e < 8; ++e) {
        unsigned int u = (unsigned int)(unsigned short)v[j][e];
        atomicAdd(&hist[bf2key(u) >> 4], 1u);
        float ex = __expf(__uint_as_float(u << 16));
        if (j & 1) es1 += ex; else es0 += ex;
      }
    }
  }
  if (t < 128) {                         // tail: chunks 8192..8319
    u16x8 v = p[8192 + t];
    #pragma unroll
    for (int e = 0; e < 8; ++e) {
      unsigned int u = (unsigned int)(unsigned short)v[e];
      atomicAdd(&hist[bf2key(u) >> 4], 1u);
      es0 += __expf(__uint_as_float(u << 16));
    }
  }
  float esum = es0 + es1;
  __syncthreads();

  // ---- chunk sums: thread t owns bins [16t, 16t+16) ----
  unsigned int S = 0;
  #pragma unroll
  for (int i = 0; i < 16; ++i) S += hist[t * 16 + i];
  csum[t] = S;
  __syncthreads();

  // ---- suffix-inclusive scan over chunks ----
  unsigned int a = S;
  #pragma unroll
  for (int s = 1; s < 256; s <<= 1) {
    unsigned int add = (t + s < 256) ? csum[t + s] : 0u;
    __syncthreads();
    a += add; csum[t] = a;
    __syncthreads();
  }

  // ---- locate exact boundary bin (unique crossing thread) ----
  int above_chunk = (t < 255) ? (int)csum[t + 1] : 0;
  if (above_chunk < TOPK_ && above_chunk + (int)S >= TOPK_) {
    int cum = above_chunk;
    #pragma unroll 1
    for (int i = 15; i >= 0; --i) {
      int c = (int)hist[t * 16 + i];
      if (cum + c >= TOPK_) { sh_bstar = t * 16 + i; sh_above = cum; break; }
      cum += c;
    }
  }
  __syncthreads();
  const unsigned int bstar = (unsigned int)sh_bstar;
  const int A = sh_above;

  // ---- sweep 2: accumulate above-b* directly, collect boundary bin ----
  float delta = 0.f;
  #pragma unroll 1
  for (int base = 0; base < 8192; base += 2048) {
    u16x8 v[8];
    #pragma unroll
    for (int j = 0; j < 8; ++j) v[j] = p[base + j * 256 + t];
    #pragma unroll
    for (int j = 0; j < 8; ++j) {
      #pragma unroll
      for (int e = 0; e < 8; ++e) {
        unsigned int u = (unsigned int)(unsigned short)v[j][e];
        unsigned int bin = bf2key(u) >> 4;
        if (bin >= bstar) {
          float val = __uint_as_float(u << 16);
          if (bin > bstar) delta += __expf(2.f * val) - __expf(val);
          else { int s = atomicAdd(&sh_cnt, 1); if (s < CAP_) vals[s] = val; }
        }
      }
    }
  }
  if (t < 128) {
    u16x8 v = p[8192 + t];
    #pragma unroll
    for (int e = 0; e < 8; ++e) {
      unsigned int u = (unsigned int)(unsigned short)v[e];
      unsigned int bin = bf2key(u) >> 4;
      if (bin >= bstar) {
        float val = __uint_as_float(u << 16);
        if (bin > bstar) delta += __expf(2.f * val) - __expf(val);
        else { int s = atomicAdd(&sh_cnt, 1); if (s < CAP_) vals[s] = val; }
      }
    }
  }
  __syncthreads();

  // ---- exact rank within boundary bin, take 128 - A ----
  int C2 = sh_cnt < CAP_ ? sh_cnt : CAP_;
  int need = TOPK_ - A;
  for (int i = t; i < C2; i += 256) {
    float v = vals[i];
    int g = 0;
    for (int k = 0; k < C2; ++k)
      g += (vals[k] > v) || (vals[k] == v && k < i);
    if (g < need) delta += __expf(2.f * v) - __expf(v);
  }

  fred[t] = esum + delta;
  __syncthreads();
  #pragma unroll
  for (int s = 128; s > 0; s >>= 1) { if (t < s) fred[t] += fred[t + s]; __syncthreads(); }

  if (t == 0) {
    float d = diag[grow];
    rowloss[grow] = logf(fred[0] + __expf(d)) - d;
  }
}

__global__ __launch_bounds__(256) void k_final(
    const float* __restrict__ rowloss, float* __restrict__ out)
{
  __shared__ float red[256];
  int t = threadIdx.x;
  float s = 0.f;
  for (int i = t; i < 2 * B_; i += 256) s += rowloss[i];
  red[t] = s;
  __syncthreads();
  for (int k = 128; k > 0; k >>= 1) { if (t < k) red[t] += red[t + k]; __syncthreads(); }
  if (t == 0) out[0] = red[0] * (1.0f / (2.0f * B_));
}

// ---------------------------------------------------------------------------
extern "C" void kernel_launch(void* const* d_in, const int* in_sizes, int n_in,
                              void* d_out, int out_size, void* d_ws, size_t ws_size,
                              hipStream_t stream)
{
  const float* rgb_feat = (const float*)d_in[0];
  const float* ir_feat  = (const float*)d_in[1];
  const float* rgb_q    = (const float*)d_in[2];
  const float* ir_q     = (const float*)d_in[3];
  const int*   epoch    = (const int*)d_in[4];

  char* ws = (char*)d_ws;
  size_t off = 0;
  auto alloc = [&](size_t bytes) -> char* {
    char* p = ws + off;
    off = (off + bytes + 255) & ~(size_t)255;
    return p;
  };

  u16* zrA = (u16*)alloc((size_t)B_ * D_ * 2);
  u16* ziA = (u16*)alloc((size_t)B_ * D_ * 2);
  u16* zrU = (u16*)alloc((size_t)B_ * D_ * 2);
  u16* ziU = (u16*)alloc((size_t)B_ * D_ * 2);
  float* diag    = (float*)alloc((size_t)2 * B_ * 4);
  float* rowloss = (float*)alloc((size_t)2 * B_ * 4);
  u16* ball = (u16*)alloc((size_t)N_ * D_ * 2);

  size_t avail = ws_size > off ? ws_size - off : 0;
  int SR = (int)(avail / ((size_t)N_ * 2));
  SR &= ~127;
  if (SR > B_) SR = B_;
  if (SR < 128) SR = 128;
  u16* slab = (u16*)(ws + off);

  k_normalize<<<dim3(2 * B_), dim3(64), 0, stream>>>(
      rgb_feat, ir_feat, epoch, zrA, ziA, zrU, ziU);

  for (int dir = 0; dir < 2; ++dir) {
    const u16*   Amat   = (dir == 0) ? zrA : ziA;
    const u16*   zOther = (dir == 0) ? ziU : zrU;
    const float* queue  = (dir == 0) ? ir_q : rgb_q;
    float* diagD = diag    + dir * B_;
    float* lossD = rowloss + dir * B_;

    k_build_ball<<<dim3((unsigned)((size_t)N_ * D_ / 8 / 256)), dim3(256), 0, stream>>>(
        zOther, queue, ball);

    for (int r0 = 0; r0 < B_; r0 += SR) {
      int cur = (B_ - r0) < SR ? (B_ - r0) : SR;
      k_gemm<<<dim3(N_ / 128, cur / 128), dim3(256), 0, stream>>>(
          Amat, ball, slab, diagD, r0);
      k_select<<<dim3(cur), dim3(256), 0, stream>>>(slab, diagD, lossD, r0);
    }
  }

  k_final<<<dim3(1), dim3(256), 0, stream>>>(rowloss, (float*)d_out);
}

// Round 4
// 367.719 us; speedup vs baseline: 2.1456x; 1.1045x over previous
//
#include <hip/hip_runtime.h>
#include <hip/hip_bf16.h>

// ---- problem constants ----
#define B_    1024
#define D_    384
#define Q_    65536
#define N_    66560            // B_ + Q_
#define TOPK_ 128

#define NBIN_ 4096             // histogram bins = key >> 4
#define CAP_  2048             // boundary-bin candidate cap

typedef __bf16 bf16x8 __attribute__((ext_vector_type(8)));
typedef float  f32x4  __attribute__((ext_vector_type(4)));
typedef unsigned short u16;
typedef u16 u16x8 __attribute__((ext_vector_type(8)));

// RNE float -> bf16 (bit-level)
__device__ __forceinline__ unsigned short f2bf(float x) {
  unsigned int u = __float_as_uint(x);
  unsigned int r = (u + 0x7fffu + ((u >> 16) & 1u)) >> 16;
  return (unsigned short)r;
}

__device__ __forceinline__ void gld_lds16(const void* g, void* l) {
  __builtin_amdgcn_global_load_lds(
      (__attribute__((address_space(1))) void*)(g),
      (__attribute__((address_space(3))) void*)(l), 16, 0, 0);
}

// monotone key from bf16 bits
__device__ __forceinline__ unsigned int bf2key(unsigned int u) {
  return u ^ ((u & 0x8000u) ? 0xFFFFu : 0x8000u);
}

// ---------------------------------------------------------------------------
// Normalize rgb/ir feats -> bf16 z (Ball role) and bf16 z/temp (A role).
// ---------------------------------------------------------------------------
__global__ __launch_bounds__(64) void k_normalize(
    const float* __restrict__ rgb, const float* __restrict__ ir,
    const int* __restrict__ ep,
    u16* __restrict__ zrA, u16* __restrict__ ziA,
    u16* __restrict__ zrU, u16* __restrict__ ziU)
{
  int r = blockIdx.x & (B_ - 1);
  bool isIr = blockIdx.x >= B_;
  const float* src = (isIr ? ir : rgb) + (size_t)r * D_;
  u16* dA = (isIr ? ziA : zrA) + (size_t)r * D_;
  u16* dU = (isIr ? ziU : zrU) + (size_t)r * D_;
  int t = threadIdx.x;
  float x[6]; float ss = 0.f;
  #pragma unroll
  for (int k = 0; k < 6; ++k) { x[k] = src[t + 64*k]; ss += x[k]*x[k]; }
  #pragma unroll
  for (int off = 32; off > 0; off >>= 1) ss += __shfl_down(ss, off);
  ss = __shfl(ss, 0);
  float inv = 1.0f / fmaxf(sqrtf(ss), 1e-12f);

  int e = ep[0];
  float temp;
  if (e >= 10) temp = 0.05f;
  else {
    float p = (float)e * 0.1f;
    temp = 0.05f + 0.075f * (1.0f + cosf(3.14159265358979323846f * p));
  }
  float itemp = 1.0f / temp;

  #pragma unroll
  for (int k = 0; k < 6; ++k) {
    float z = x[k] * inv;
    dU[t + 64*k] = f2bf(z);
    dA[t + 64*k] = f2bf(z * itemp);
  }
}

// ---------------------------------------------------------------------------
// Build Ball bf16 [N_][D_] = [z_other (bf16 copy) ; queue (f32->bf16)]
// ---------------------------------------------------------------------------
__global__ __launch_bounds__(256) void k_build_ball(
    const u16* __restrict__ zU, const float* __restrict__ queue,
    u16* __restrict__ ball)
{
  size_t i = ((size_t)blockIdx.x * 256 + threadIdx.x) * 8;
  const size_t zElems = (size_t)B_ * D_;
  if (i < zElems) {
    *(uint4*)(ball + i) = *(const uint4*)(zU + i);
  } else {
    const float* q = queue + (i - zElems);
    float4 a = *(const float4*)q;
    float4 b = *(const float4*)(q + 4);
    u16x8 o;
    o[0] = f2bf(a.x); o[1] = f2bf(a.y); o[2] = f2bf(a.z); o[3] = f2bf(a.w);
    o[4] = f2bf(b.x); o[5] = f2bf(b.y); o[6] = f2bf(b.z); o[7] = f2bf(b.w);
    *(u16x8*)(ball + i) = o;
  }
}

// ---------------------------------------------------------------------------
// bf16 MFMA GEMM -> bf16 logits slab. 128x128 tile, BK=64, 4 waves (2x2).
// 1D grid, swizzled: M-tiles innermost (consecutive blocks share the ball
// panel -> L2 reuse), XCD-chunked (each XCD gets a contiguous run of panels).
// Epilogue: extract diag (f32) then poison with -60.
// ---------------------------------------------------------------------------
#define BK_ 64
__global__ __launch_bounds__(256) void k_gemm(
    const u16* __restrict__ A,     // [B_][D_] scaled bf16
    const u16* __restrict__ ball,  // [N_][D_] bf16
    u16* __restrict__ C,           // [SR][N_] bf16 logits
    float* __restrict__ diag,      // [B_]
    int r0, int mtiles)
{
  __shared__ u16 As[128 * BK_];
  __shared__ u16 Bs[128 * BK_];

  // ---- swizzle: M-inner + XCD-chunked (nwg = 520*mtiles, divisible by 8) ----
  int bid = blockIdx.x;
  int nwg = gridDim.x;
  int cpx = nwg >> 3;                   // chunk per XCD
  int wgid = (bid & 7) * cpx + (bid >> 3);
  int nt = wgid / mtiles;               // N-panel index 0..519
  int mt = wgid - nt * mtiles;          // M-tile index

  const int tid  = threadIdx.x;
  const int wave = tid >> 6, lane = tid & 63;
  const int wm = wave >> 1, wn = wave & 1;
  const int mbase = mt * 128;
  const int nbase = nt * 128;
  const u16* Ab = A    + (size_t)(r0 + mbase) * D_;
  const u16* Bb = ball + (size_t)nbase * D_;

  f32x4 acc[4][4];
  #pragma unroll
  for (int m = 0; m < 4; ++m)
    #pragma unroll
    for (int n = 0; n < 4; ++n)
      #pragma unroll
      for (int r = 0; r < 4; ++r) acc[m][n][r] = 0.0f;

  for (int ks = 0; ks < D_; ks += BK_) {
    #pragma unroll
    for (int i = 0; i < 4; ++i) {
      int f = i * 256 + tid;
      int rr = f >> 3, c = f & 7;
      const u16* ga = Ab + (size_t)rr * D_ + ks + c * 8;
      const u16* gb = Bb + (size_t)rr * D_ + ks + c * 8;
      u16* la = As + (size_t)(i * 256 + wave * 64) * 8;
      u16* lb = Bs + (size_t)(i * 256 + wave * 64) * 8;
      gld_lds16(ga, la);
      gld_lds16(gb, lb);
    }
    __syncthreads();

    const int lr = lane & 15, lk = (lane >> 4) * 8;
    #pragma unroll
    for (int kk = 0; kk < BK_; kk += 32) {
      bf16x8 af[4], bq[4];
      #pragma unroll
      for (int m = 0; m < 4; ++m)
        af[m] = *(const bf16x8*)(As + (wm*64 + m*16 + lr) * BK_ + kk + lk);
      #pragma unroll
      for (int n = 0; n < 4; ++n)
        bq[n] = *(const bf16x8*)(Bs + (wn*64 + n*16 + lr) * BK_ + kk + lk);
      #pragma unroll
      for (int m = 0; m < 4; ++m)
        #pragma unroll
        for (int n = 0; n < 4; ++n)
          acc[m][n] = __builtin_amdgcn_mfma_f32_16x16x32_bf16(af[m], bq[n], acc[m][n], 0, 0, 0);
    }
    __syncthreads();
  }

  // D layout: col = lane&15, row = (lane>>4)*4 + reg.
  const int lr = lane & 15;
  const int rowq = (lane >> 4) * 4;
  #pragma unroll
  for (int m = 0; m < 4; ++m) {
    #pragma unroll
    for (int n = 0; n < 4; ++n) {
      int col = nbase + wn*64 + n*16 + lr;
      #pragma unroll
      for (int r = 0; r < 4; ++r) {
        int srow = mbase + wm*64 + m*16 + rowq + r;
        float x = acc[m][n][r];
        int grow = r0 + srow;
        if (col == grow) { diag[grow] = x; x = -60.0f; }
        C[(size_t)srow * N_ + col] = f2bf(x);
      }
    }
  }
}

// ---------------------------------------------------------------------------
// Per-row exact top-128 + exp-sum + loss. 2-sweep radix select.
// ---------------------------------------------------------------------------
__global__ __launch_bounds__(256) void k_select(
    const u16* __restrict__ C, const float* __restrict__ diag,
    float* __restrict__ rowloss, int r0)
{
  __shared__ unsigned int hist[NBIN_];   // 16 KB
  __shared__ float vals[CAP_];           // 8 KB
  __shared__ float fred[256];
  __shared__ unsigned int csum[256];
  __shared__ int sh_bstar, sh_above, sh_cnt;

  const int t = threadIdx.x;
  const int grow = r0 + blockIdx.x;
  const u16x8* p = (const u16x8*)(C + (size_t)blockIdx.x * N_);

  uint4* h4 = (uint4*)hist;
  #pragma unroll
  for (int i = 0; i < 4; ++i) h4[i * 256 + t] = make_uint4(0,0,0,0);
  if (t == 0) sh_cnt = 0;
  __syncthreads();

  // ---- sweep 1: expsum + histogram ----
  float es0 = 0.f, es1 = 0.f;
  #pragma unroll 1
  for (int base = 0; base < 8192; base += 2048) {
    u16x8 v[8];
    #pragma unroll
    for (int j = 0; j < 8; ++j) v[j] = p[base + j * 256 + t];
    #pragma unroll
    for (int j = 0; j < 8; ++j) {
      #pragma unroll
      for (int e = 0; e < 8; ++e) {
        unsigned int u = (unsigned int)(unsigned short)v[j][e];
        atomicAdd(&hist[bf2key(u) >> 4], 1u);
        float ex = __expf(__uint_as_float(u << 16));
        if (j & 1) es1 += ex; else es0 += ex;
      }
    }
  }
  if (t < 128) {                         // tail: chunks 8192..8319
    u16x8 v = p[8192 + t];
    #pragma unroll
    for (int e = 0; e < 8; ++e) {
      unsigned int u = (unsigned int)(unsigned short)v[e];
      atomicAdd(&hist[bf2key(u) >> 4], 1u);
      es0 += __expf(__uint_as_float(u << 16));
    }
  }
  float esum = es0 + es1;
  __syncthreads();

  // ---- chunk sums: thread t owns bins [16t, 16t+16) ----
  unsigned int S = 0;
  #pragma unroll
  for (int i = 0; i < 16; ++i) S += hist[t * 16 + i];
  csum[t] = S;
  __syncthreads();

  // ---- suffix-inclusive scan over chunks ----
  unsigned int a = S;
  #pragma unroll
  for (int s = 1; s < 256; s <<= 1) {
    unsigned int add = (t + s < 256) ? csum[t + s] : 0u;
    __syncthreads();
    a += add; csum[t] = a;
    __syncthreads();
  }

  // ---- locate exact boundary bin (unique crossing thread) ----
  int above_chunk = (t < 255) ? (int)csum[t + 1] : 0;
  if (above_chunk < TOPK_ && above_chunk + (int)S >= TOPK_) {
    int cum = above_chunk;
    #pragma unroll 1
    for (int i = 15; i >= 0; --i) {
      int c = (int)hist[t * 16 + i];
      if (cum + c >= TOPK_) { sh_bstar = t * 16 + i; sh_above = cum; break; }
      cum += c;
    }
  }
  __syncthreads();
  const unsigned int bstar = (unsigned int)sh_bstar;
  const int A = sh_above;

  // ---- sweep 2: accumulate above-b* directly, collect boundary bin ----
  float delta = 0.f;
  #pragma unroll 1
  for (int base = 0; base < 8192; base += 2048) {
    u16x8 v[8];
    #pragma unroll
    for (int j = 0; j < 8; ++j) v[j] = p[base + j * 256 + t];
    #pragma unroll
    for (int j = 0; j < 8; ++j) {
      #pragma unroll
      for (int e = 0; e < 8; ++e) {
        unsigned int u = (unsigned int)(unsigned short)v[j][e];
        unsigned int bin = bf2key(u) >> 4;
        if (bin >= bstar) {
          float val = __uint_as_float(u << 16);
          if (bin > bstar) delta += __expf(2.f * val) - __expf(val);
          else { int s = atomicAdd(&sh_cnt, 1); if (s < CAP_) vals[s] = val; }
        }
      }
    }
  }
  if (t < 128) {
    u16x8 v = p[8192 + t];
    #pragma unroll
    for (int e = 0; e < 8; ++e) {
      unsigned int u = (unsigned int)(unsigned short)v[e];
      unsigned int bin = bf2key(u) >> 4;
      if (bin >= bstar) {
        float val = __uint_as_float(u << 16);
        if (bin > bstar) delta += __expf(2.f * val) - __expf(val);
        else { int s = atomicAdd(&sh_cnt, 1); if (s < CAP_) vals[s] = val; }
      }
    }
  }
  __syncthreads();

  // ---- exact rank within boundary bin, take 128 - A ----
  int C2 = sh_cnt < CAP_ ? sh_cnt : CAP_;
  int need = TOPK_ - A;
  for (int i = t; i < C2; i += 256) {
    float v = vals[i];
    int g = 0;
    for (int k = 0; k < C2; ++k)
      g += (vals[k] > v) || (vals[k] == v && k < i);
    if (g < need) delta += __expf(2.f * v) - __expf(v);
  }

  fred[t] = esum + delta;
  __syncthreads();
  #pragma unroll
  for (int s = 128; s > 0; s >>= 1) { if (t < s) fred[t] += fred[t + s]; __syncthreads(); }

  if (t == 0) {
    float d = diag[grow];
    rowloss[grow] = logf(fred[0] + __expf(d)) - d;
  }
}

__global__ __launch_bounds__(256) void k_final(
    const float* __restrict__ rowloss, float* __restrict__ out)
{
  __shared__ float red[256];
  int t = threadIdx.x;
  float s = 0.f;
  for (int i = t; i < 2 * B_; i += 256) s += rowloss[i];
  red[t] = s;
  __syncthreads();
  for (int k = 128; k > 0; k >>= 1) { if (t < k) red[t] += red[t + k]; __syncthreads(); }
  if (t == 0) out[0] = red[0] * (1.0f / (2.0f * B_));
}

// ---------------------------------------------------------------------------
extern "C" void kernel_launch(void* const* d_in, const int* in_sizes, int n_in,
                              void* d_out, int out_size, void* d_ws, size_t ws_size,
                              hipStream_t stream)
{
  const float* rgb_feat = (const float*)d_in[0];
  const float* ir_feat  = (const float*)d_in[1];
  const float* rgb_q    = (const float*)d_in[2];
  const float* ir_q     = (const float*)d_in[3];
  const int*   epoch    = (const int*)d_in[4];

  char* ws = (char*)d_ws;
  size_t off = 0;
  auto alloc = [&](size_t bytes) -> char* {
    char* p = ws + off;
    off = (off + bytes + 255) & ~(size_t)255;
    return p;
  };

  u16* zrA = (u16*)alloc((size_t)B_ * D_ * 2);
  u16* ziA = (u16*)alloc((size_t)B_ * D_ * 2);
  u16* zrU = (u16*)alloc((size_t)B_ * D_ * 2);
  u16* ziU = (u16*)alloc((size_t)B_ * D_ * 2);
  float* diag    = (float*)alloc((size_t)2 * B_ * 4);
  float* rowloss = (float*)alloc((size_t)2 * B_ * 4);
  u16* ball = (u16*)alloc((size_t)N_ * D_ * 2);

  size_t avail = ws_size > off ? ws_size - off : 0;
  int SR = (int)(avail / ((size_t)N_ * 2));
  SR &= ~127;
  if (SR > B_) SR = B_;
  if (SR < 128) SR = 128;
  u16* slab = (u16*)(ws + off);

  k_normalize<<<dim3(2 * B_), dim3(64), 0, stream>>>(
      rgb_feat, ir_feat, epoch, zrA, ziA, zrU, ziU);

  for (int dir = 0; dir < 2; ++dir) {
    const u16*   Amat   = (dir == 0) ? zrA : ziA;
    const u16*   zOther = (dir == 0) ? ziU : zrU;
    const float* queue  = (dir == 0) ? ir_q : rgb_q;
    float* diagD = diag    + dir * B_;
    float* lossD = rowloss + dir * B_;

    k_build_ball<<<dim3((unsigned)((size_t)N_ * D_ / 8 / 256)), dim3(256), 0, stream>>>(
        zOther, queue, ball);

    for (int r0 = 0; r0 < B_; r0 += SR) {
      int cur = (B_ - r0) < SR ? (B_ - r0) : SR;
      int mtiles = cur / 128;
      int nwg = (N_ / 128) * mtiles;   // 520 * mtiles, divisible by 8
      k_gemm<<<dim3(nwg), dim3(256), 0, stream>>>(
          Amat, ball, slab, diagD, r0, mtiles);
      k_select<<<dim3(cur), dim3(256), 0, stream>>>(slab, diagD, lossD, r0);
    }
  }

  k_final<<<dim3(1), dim3(256), 0, stream>>>(rowloss, (float*)d_out);
}

// Round 5
// 344.656 us; speedup vs baseline: 2.2892x; 1.0669x over previous
//
#include <hip/hip_runtime.h>
#include <hip/hip_bf16.h>

// ---- problem constants ----
#define B_    1024
#define D_    384
#define Q_    65536
#define N_    66560            // B_ + Q_
#define TOPK_ 128

#define NBIN_ 4096             // histogram bins = key >> 4
#define CAP_  2048             // boundary-bin candidate cap

typedef __bf16 bf16x8 __attribute__((ext_vector_type(8)));
typedef float  f32x4  __attribute__((ext_vector_type(4)));
typedef unsigned short u16;
typedef u16 u16x8 __attribute__((ext_vector_type(8)));

// RNE float -> bf16 (bit-level)
__device__ __forceinline__ unsigned short f2bf(float x) {
  unsigned int u = __float_as_uint(x);
  unsigned int r = (u + 0x7fffu + ((u >> 16) & 1u)) >> 16;
  return (unsigned short)r;
}

__device__ __forceinline__ void gld_lds16(const void* g, void* l) {
  __builtin_amdgcn_global_load_lds(
      (__attribute__((address_space(1))) void*)(g),
      (__attribute__((address_space(3))) void*)(l), 16, 0, 0);
}

// monotone key from bf16 bits
__device__ __forceinline__ unsigned int bf2key(unsigned int u) {
  return u ^ ((u & 0x8000u) ? 0xFFFFu : 0x8000u);
}

// ---------------------------------------------------------------------------
// Normalize rgb/ir feats -> bf16 z (Ball role) and bf16 z/temp (A role).
// ---------------------------------------------------------------------------
__global__ __launch_bounds__(64) void k_normalize(
    const float* __restrict__ rgb, const float* __restrict__ ir,
    const int* __restrict__ ep,
    u16* __restrict__ zrA, u16* __restrict__ ziA,
    u16* __restrict__ zrU, u16* __restrict__ ziU)
{
  int r = blockIdx.x & (B_ - 1);
  bool isIr = blockIdx.x >= B_;
  const float* src = (isIr ? ir : rgb) + (size_t)r * D_;
  u16* dA = (isIr ? ziA : zrA) + (size_t)r * D_;
  u16* dU = (isIr ? ziU : zrU) + (size_t)r * D_;
  int t = threadIdx.x;
  float x[6]; float ss = 0.f;
  #pragma unroll
  for (int k = 0; k < 6; ++k) { x[k] = src[t + 64*k]; ss += x[k]*x[k]; }
  #pragma unroll
  for (int off = 32; off > 0; off >>= 1) ss += __shfl_down(ss, off);
  ss = __shfl(ss, 0);
  float inv = 1.0f / fmaxf(sqrtf(ss), 1e-12f);

  int e = ep[0];
  float temp;
  if (e >= 10) temp = 0.05f;
  else {
    float p = (float)e * 0.1f;
    temp = 0.05f + 0.075f * (1.0f + cosf(3.14159265358979323846f * p));
  }
  float itemp = 1.0f / temp;

  #pragma unroll
  for (int k = 0; k < 6; ++k) {
    float z = x[k] * inv;
    dU[t + 64*k] = f2bf(z);
    dA[t + 64*k] = f2bf(z * itemp);
  }
}

// ---------------------------------------------------------------------------
// Build Ball bf16 [N_][D_] = [z_other (bf16 copy) ; queue (f32->bf16)]
// ---------------------------------------------------------------------------
__global__ __launch_bounds__(256) void k_build_ball(
    const u16* __restrict__ zU, const float* __restrict__ queue,
    u16* __restrict__ ball)
{
  size_t i = ((size_t)blockIdx.x * 256 + threadIdx.x) * 8;
  const size_t zElems = (size_t)B_ * D_;
  if (i < zElems) {
    *(uint4*)(ball + i) = *(const uint4*)(zU + i);
  } else {
    const float* q = queue + (i - zElems);
    float4 a = *(const float4*)q;
    float4 b = *(const float4*)(q + 4);
    u16x8 o;
    o[0] = f2bf(a.x); o[1] = f2bf(a.y); o[2] = f2bf(a.z); o[3] = f2bf(a.w);
    o[4] = f2bf(b.x); o[5] = f2bf(b.y); o[6] = f2bf(b.z); o[7] = f2bf(b.w);
    *(u16x8*)(ball + i) = o;
  }
}

// ---------------------------------------------------------------------------
// bf16 MFMA GEMM -> bf16 logits slab. 128x128 tile, BK=64, 4 waves (2x2).
// T1: 1D grid, M-tiles innermost + XCD-chunked.
// T2: st-style XOR swizzle (byte ^= (row&7)<<4) — LDS dest stays linear for
//     global_load_lds; the GLOBAL source column is pre-swizzled (rule 21),
//     and fragment ds_reads apply the same XOR. 16-way -> 2-way conflicts.
// Epilogue: extract diag (f32) then poison with -60.
// ---------------------------------------------------------------------------
#define BK_ 64
__global__ __launch_bounds__(256) void k_gemm(
    const u16* __restrict__ A,     // [B_][D_] scaled bf16
    const u16* __restrict__ ball,  // [N_][D_] bf16
    u16* __restrict__ C,           // [SR][N_] bf16 logits
    float* __restrict__ diag,      // [B_]
    int r0, int mtiles)
{
  __shared__ u16 As[128 * BK_];
  __shared__ u16 Bs[128 * BK_];

  // ---- swizzle: M-inner + XCD-chunked (nwg = 520*mtiles, divisible by 8) ----
  int bid = blockIdx.x;
  int nwg = gridDim.x;
  int cpx = nwg >> 3;                   // chunk per XCD
  int wgid = (bid & 7) * cpx + (bid >> 3);
  int nt = wgid / mtiles;               // N-panel index 0..519
  int mt = wgid - nt * mtiles;          // M-tile index

  const int tid  = threadIdx.x;
  const int wave = tid >> 6, lane = tid & 63;
  const int wm = wave >> 1, wn = wave & 1;
  const int mbase = mt * 128;
  const int nbase = nt * 128;
  const u16* Ab = A    + (size_t)(r0 + mbase) * D_;
  const u16* Bb = ball + (size_t)nbase * D_;

  f32x4 acc[4][4];
  #pragma unroll
  for (int m = 0; m < 4; ++m)
    #pragma unroll
    for (int n = 0; n < 4; ++n)
      #pragma unroll
      for (int r = 0; r < 4; ++r) acc[m][n][r] = 0.0f;

  for (int ks = 0; ks < D_; ks += BK_) {
    #pragma unroll
    for (int i = 0; i < 4; ++i) {
      int f = i * 256 + tid;
      int rr = f >> 3, c = f & 7;
      // pre-swizzled global column: byte (c*16) ^ ((rr&7)<<4), back to elems
      int koff = (((c * 16) ^ ((rr & 7) << 4)) >> 1);
      const u16* ga = Ab + (size_t)rr * D_ + ks + koff;
      const u16* gb = Bb + (size_t)rr * D_ + ks + koff;
      u16* la = As + (size_t)(i * 256 + wave * 64) * 8;   // linear dest
      u16* lb = Bs + (size_t)(i * 256 + wave * 64) * 8;
      gld_lds16(ga, la);
      gld_lds16(gb, lb);
    }
    __syncthreads();

    const int lr = lane & 15, lk = (lane >> 4) * 8;
    #pragma unroll
    for (int kk = 0; kk < BK_; kk += 32) {
      bf16x8 af[4], bq[4];
      const int kb = (kk + lk) * 2;     // byte column within the 128B row
      #pragma unroll
      for (int m = 0; m < 4; ++m) {
        int row = wm*64 + m*16 + lr;
        af[m] = *(const bf16x8*)((const char*)As + row * 128 + (kb ^ ((row & 7) << 4)));
      }
      #pragma unroll
      for (int n = 0; n < 4; ++n) {
        int row = wn*64 + n*16 + lr;
        bq[n] = *(const bf16x8*)((const char*)Bs + row * 128 + (kb ^ ((row & 7) << 4)));
      }
      #pragma unroll
      for (int m = 0; m < 4; ++m)
        #pragma unroll
        for (int n = 0; n < 4; ++n)
          acc[m][n] = __builtin_amdgcn_mfma_f32_16x16x32_bf16(af[m], bq[n], acc[m][n], 0, 0, 0);
    }
    __syncthreads();
  }

  // D layout: col = lane&15, row = (lane>>4)*4 + reg.
  const int lr = lane & 15;
  const int rowq = (lane >> 4) * 4;
  #pragma unroll
  for (int m = 0; m < 4; ++m) {
    #pragma unroll
    for (int n = 0; n < 4; ++n) {
      int col = nbase + wn*64 + n*16 + lr;
      #pragma unroll
      for (int r = 0; r < 4; ++r) {
        int srow = mbase + wm*64 + m*16 + rowq + r;
        float x = acc[m][n][r];
        int grow = r0 + srow;
        if (col == grow) { diag[grow] = x; x = -60.0f; }
        C[(size_t)srow * N_ + col] = f2bf(x);
      }
    }
  }
}

// ---------------------------------------------------------------------------
// Per-row exact top-128 + exp-sum + loss. 2-sweep radix select.
// ---------------------------------------------------------------------------
__global__ __launch_bounds__(256) void k_select(
    const u16* __restrict__ C, const float* __restrict__ diag,
    float* __restrict__ rowloss, int r0)
{
  __shared__ unsigned int hist[NBIN_];   // 16 KB
  __shared__ float vals[CAP_];           // 8 KB
  __shared__ float fred[256];
  __shared__ unsigned int csum[256];
  __shared__ int sh_bstar, sh_above, sh_cnt;

  const int t = threadIdx.x;
  const int grow = r0 + blockIdx.x;
  const u16x8* p = (const u16x8*)(C + (size_t)blockIdx.x * N_);

  uint4* h4 = (uint4*)hist;
  #pragma unroll
  for (int i = 0; i < 4; ++i) h4[i * 256 + t] = make_uint4(0,0,0,0);
  if (t == 0) sh_cnt = 0;
  __syncthreads();

  // ---- sweep 1: expsum + histogram ----
  float es0 = 0.f, es1 = 0.f;
  #pragma unroll 1
  for (int base = 0; base < 8192; base += 2048) {
    u16x8 v[8];
    #pragma unroll
    for (int j = 0; j < 8; ++j) v[j] = p[base + j * 256 + t];
    #pragma unroll
    for (int j = 0; j < 8; ++j) {
      #pragma unroll
      for (int e = 0; e < 8; ++e) {
        unsigned int u = (unsigned int)(unsigned short)v[j][e];
        atomicAdd(&hist[bf2key(u) >> 4], 1u);
        float ex = __expf(__uint_as_float(u << 16));
        if (j & 1) es1 += ex; else es0 += ex;
      }
    }
  }
  if (t < 128) {                         // tail: chunks 8192..8319
    u16x8 v = p[8192 + t];
    #pragma unroll
    for (int e = 0; e < 8; ++e) {
      unsigned int u = (unsigned int)(unsigned short)v[e];
      atomicAdd(&hist[bf2key(u) >> 4], 1u);
      es0 += __expf(__uint_as_float(u << 16));
    }
  }
  float esum = es0 + es1;
  __syncthreads();

  // ---- chunk sums: thread t owns bins [16t, 16t+16) ----
  unsigned int S = 0;
  #pragma unroll
  for (int i = 0; i < 16; ++i) S += hist[t * 16 + i];
  csum[t] = S;
  __syncthreads();

  // ---- suffix-inclusive scan over chunks ----
  unsigned int a = S;
  #pragma unroll
  for (int s = 1; s < 256; s <<= 1) {
    unsigned int add = (t + s < 256) ? csum[t + s] : 0u;
    __syncthreads();
    a += add; csum[t] = a;
    __syncthreads();
  }

  // ---- locate exact boundary bin (unique crossing thread) ----
  int above_chunk = (t < 255) ? (int)csum[t + 1] : 0;
  if (above_chunk < TOPK_ && above_chunk + (int)S >= TOPK_) {
    int cum = above_chunk;
    #pragma unroll 1
    for (int i = 15; i >= 0; --i) {
      int c = (int)hist[t * 16 + i];
      if (cum + c >= TOPK_) { sh_bstar = t * 16 + i; sh_above = cum; break; }
      cum += c;
    }
  }
  __syncthreads();
  const unsigned int bstar = (unsigned int)sh_bstar;
  const int A = sh_above;

  // ---- sweep 2: accumulate above-b* directly, collect boundary bin ----
  float delta = 0.f;
  #pragma unroll 1
  for (int base = 0; base < 8192; base += 2048) {
    u16x8 v[8];
    #pragma unroll
    for (int j = 0; j < 8; ++j) v[j] = p[base + j * 256 + t];
    #pragma unroll
    for (int j = 0; j < 8; ++j) {
      #pragma unroll
      for (int e = 0; e < 8; ++e) {
        unsigned int u = (unsigned int)(unsigned short)v[j][e];
        unsigned int bin = bf2key(u) >> 4;
        if (bin >= bstar) {
          float val = __uint_as_float(u << 16);
          if (bin > bstar) delta += __expf(2.f * val) - __expf(val);
          else { int s = atomicAdd(&sh_cnt, 1); if (s < CAP_) vals[s] = val; }
        }
      }
    }
  }
  if (t < 128) {
    u16x8 v = p[8192 + t];
    #pragma unroll
    for (int e = 0; e < 8; ++e) {
      unsigned int u = (unsigned int)(unsigned short)v[e];
      unsigned int bin = bf2key(u) >> 4;
      if (bin >= bstar) {
        float val = __uint_as_float(u << 16);
        if (bin > bstar) delta += __expf(2.f * val) - __expf(val);
        else { int s = atomicAdd(&sh_cnt, 1); if (s < CAP_) vals[s] = val; }
      }
    }
  }
  __syncthreads();

  // ---- exact rank within boundary bin, take 128 - A ----
  int C2 = sh_cnt < CAP_ ? sh_cnt : CAP_;
  int need = TOPK_ - A;
  for (int i = t; i < C2; i += 256) {
    float v = vals[i];
    int g = 0;
    for (int k = 0; k < C2; ++k)
      g += (vals[k] > v) || (vals[k] == v && k < i);
    if (g < need) delta += __expf(2.f * v) - __expf(v);
  }

  fred[t] = esum + delta;
  __syncthreads();
  #pragma unroll
  for (int s = 128; s > 0; s >>= 1) { if (t < s) fred[t] += fred[t + s]; __syncthreads(); }

  if (t == 0) {
    float d = diag[grow];
    rowloss[grow] = logf(fred[0] + __expf(d)) - d;
  }
}

__global__ __launch_bounds__(256) void k_final(
    const float* __restrict__ rowloss, float* __restrict__ out)
{
  __shared__ float red[256];
  int t = threadIdx.x;
  float s = 0.f;
  for (int i = t; i < 2 * B_; i += 256) s += rowloss[i];
  red[t] = s;
  __syncthreads();
  for (int k = 128; k > 0; k >>= 1) { if (t < k) red[t] += red[t + k]; __syncthreads(); }
  if (t == 0) out[0] = red[0] * (1.0f / (2.0f * B_));
}

// ---------------------------------------------------------------------------
extern "C" void kernel_launch(void* const* d_in, const int* in_sizes, int n_in,
                              void* d_out, int out_size, void* d_ws, size_t ws_size,
                              hipStream_t stream)
{
  const float* rgb_feat = (const float*)d_in[0];
  const float* ir_feat  = (const float*)d_in[1];
  const float* rgb_q    = (const float*)d_in[2];
  const float* ir_q     = (const float*)d_in[3];
  const int*   epoch    = (const int*)d_in[4];

  char* ws = (char*)d_ws;
  size_t off = 0;
  auto alloc = [&](size_t bytes) -> char* {
    char* p = ws + off;
    off = (off + bytes + 255) & ~(size_t)255;
    return p;
  };

  u16* zrA = (u16*)alloc((size_t)B_ * D_ * 2);
  u16* ziA = (u16*)alloc((size_t)B_ * D_ * 2);
  u16* zrU = (u16*)alloc((size_t)B_ * D_ * 2);
  u16* ziU = (u16*)alloc((size_t)B_ * D_ * 2);
  float* diag    = (float*)alloc((size_t)2 * B_ * 4);
  float* rowloss = (float*)alloc((size_t)2 * B_ * 4);
  u16* ball = (u16*)alloc((size_t)N_ * D_ * 2);

  size_t avail = ws_size > off ? ws_size - off : 0;
  int SR = (int)(avail / ((size_t)N_ * 2));
  SR &= ~127;
  if (SR > B_) SR = B_;
  if (SR < 128) SR = 128;
  u16* slab = (u16*)(ws + off);

  k_normalize<<<dim3(2 * B_), dim3(64), 0, stream>>>(
      rgb_feat, ir_feat, epoch, zrA, ziA, zrU, ziU);

  for (int dir = 0; dir < 2; ++dir) {
    const u16*   Amat   = (dir == 0) ? zrA : ziA;
    const u16*   zOther = (dir == 0) ? ziU : zrU;
    const float* queue  = (dir == 0) ? ir_q : rgb_q;
    float* diagD = diag    + dir * B_;
    float* lossD = rowloss + dir * B_;

    k_build_ball<<<dim3((unsigned)((size_t)N_ * D_ / 8 / 256)), dim3(256), 0, stream>>>(
        zOther, queue, ball);

    for (int r0 = 0; r0 < B_; r0 += SR) {
      int cur = (B_ - r0) < SR ? (B_ - r0) : SR;
      int mtiles = cur / 128;
      int nwg = (N_ / 128) * mtiles;   // 520 * mtiles, divisible by 8
      k_gemm<<<dim3(nwg), dim3(256), 0, stream>>>(
          Amat, ball, slab, diagD, r0, mtiles);
      k_select<<<dim3(cur), dim3(256), 0, stream>>>(slab, diagD, lossD, r0);
    }
  }

  k_final<<<dim3(1), dim3(256), 0, stream>>>(rowloss, (float*)d_out);
}